// Round 5
// baseline (359.941 us; speedup 1.0000x reference)
//
#include <hip/hip_runtime.h>
#include <math.h>

typedef unsigned int u32;
typedef unsigned short u16;
typedef __attribute__((ext_vector_type(8))) short bf16x8;   // 8 bf16 in 4 VGPRs
typedef __attribute__((ext_vector_type(4))) float f32x4;

__device__ inline u16 f2bf(float x) {  // round-to-nearest-even
    union { float f; u32 u; } v; v.f = x;
    u32 r = v.u + 0x7FFFu + ((v.u >> 16) & 1u);
    return (u16)(r >> 16);
}
__device__ inline float4 bf4_to_f4(uint2 p) {
    float4 r;
    r.x = __uint_as_float(p.x << 16);
    r.y = __uint_as_float(p.x & 0xffff0000u);
    r.z = __uint_as_float(p.y << 16);
    r.w = __uint_as_float(p.y & 0xffff0000u);
    return r;
}

// ---------------------------------------------------------------------------
// Clifford GNN message passing, fully linearized:
//   agg[n] = sum_e w_e*(h[src] .* r[rel]),  w_e = gate(rel)*norm(e)
//   out    = UL(ML(agg) + h + msg_b*ws) + upd_b
//          = (Ku.Km).agg + Ku.h + ws*(Ku.msg_b) + upd_b        (UL linear!)
// so one K=512 MFMA GEMM on [agg_row | h_row] with Kcomb = [Ku.Km | Ku],
// rows pre-permuted by the output channel-major permutation (free coalescing).
// ---------------------------------------------------------------------------

// Mf[k*256+i] = M[k][i] fp32 (message Clifford matrix, row k = output idx)
__global__ void build_m_kernel(const float* __restrict__ msg_w, float* __restrict__ Mf) {
    const int   s_tab[16] = {0,1,2,3, 1,0,3,2, 2,3,0,1, 3,2,1,0};
    const float g_tab[16] = {1.f,1.f,1.f,-1.f, 1.f,1.f,-1.f,1.f,
                             1.f,1.f,1.f,-1.f, 1.f,1.f,1.f,1.f};
    int idx = blockIdx.x * 256 + threadIdx.x;   // idx = k*256 + i
    int k = idx >> 8, i = idx & 255;
    int ob = k >> 6, oc = k & 63, ib = i >> 6, ic = i & 63;
    int t = ob * 4 + ib;
    Mf[idx] = g_tab[t] * msg_w[s_tab[t] * 4096 + oc * 64 + ic];
}

// Block p builds output-permuted row p of Kcomb (512 wide bf16) + c0[p], c1[p].
// j = (p&3)*64 + (p>>2);  Kcomb[p][0:256] = (U.M)[j][:], Kcomb[p][256:512]=U[j][:]
__global__ __launch_bounds__(256) void build_comb_kernel(
    const float* __restrict__ upd_w, const float* __restrict__ upd_b,
    const float* __restrict__ msg_b, const float* __restrict__ Mf,
    u16* __restrict__ Kcomb, float* __restrict__ c0, float* __restrict__ c1) {
    const int   s_tab[16] = {0,1,2,3, 1,0,3,2, 2,3,0,1, 3,2,1,0};
    const float g_tab[16] = {1.f,1.f,1.f,-1.f, 1.f,1.f,-1.f,1.f,
                             1.f,1.f,1.f,-1.f, 1.f,1.f,1.f,1.f};
    __shared__ float U_s[256];
    __shared__ float wred[4];
    int p = blockIdx.x;
    int j = (p & 3) * 64 + (p >> 2);
    int tid = threadIdx.x;
    {
        int ob = j >> 6, oc = j & 63, ib = tid >> 6, ic = tid & 63;
        int t = ob * 4 + ib;
        U_s[tid] = g_tab[t] * upd_w[s_tab[t] * 4096 + oc * 64 + ic];
    }
    __syncthreads();
    float acc = 0.f;
#pragma unroll 8
    for (int k = 0; k < 256; ++k) acc += U_s[k] * Mf[k * 256 + tid];
    Kcomb[(size_t)p * 512 + tid] = f2bf(acc);
    Kcomb[(size_t)p * 512 + 256 + tid] = f2bf(U_s[tid]);
    float part = U_s[tid] * msg_b[tid];
    int lane = tid & 63, wv = tid >> 6;
#pragma unroll
    for (int d = 32; d > 0; d >>= 1) part += __shfl_down(part, d);
    if (lane == 0) wred[wv] = part;
    __syncthreads();
    if (tid == 0) { c1[p] = wred[0] + wred[1] + wred[2] + wred[3]; c0[p] = upd_b[j]; }
}

// gate[r] = sigmoid( sum_j rel_emb[r, j] * gate_w[(j&63)*4 + (j>>6)] + gate_b )
__global__ void gate_kernel(const float* __restrict__ rel_emb,
                            const float* __restrict__ gate_w,
                            const float* __restrict__ gate_b,
                            float* __restrict__ gate, int R) {
    int wv = threadIdx.x >> 6, lane = threadIdx.x & 63;
    int r = blockIdx.x * 4 + wv;
    if (r >= R) return;
    float4 rv = *(const float4*)(rel_emb + (size_t)r * 256 + lane * 4);
    float s = 0.f;
    float rvv[4] = {rv.x, rv.y, rv.z, rv.w};
#pragma unroll
    for (int c = 0; c < 4; ++c) {
        int j = lane * 4 + c;
        s += rvv[c] * gate_w[(j & 63) * 4 + (j >> 6)];
    }
#pragma unroll
    for (int d = 32; d > 0; d >>= 1) s += __shfl_down(s, d);
    if (lane == 0) gate[r] = 1.0f / (1.0f + expf(-(s + gate_b[0])));
}

__global__ void degree_kernel(const int* __restrict__ ei, int E,
                              u32* __restrict__ deg_src, u32* __restrict__ deg_dst) {
    int e = blockIdx.x * 256 + threadIdx.x;
    if (e >= E) return;
    atomicAdd(&deg_src[ei[e]], 1u);
    atomicAdd(&deg_dst[ei[E + e]], 1u);
}

// Parallel bucket allocator (order irrelevant, only disjointness matters).
__global__ void alloc_kernel(const u32* __restrict__ deg, u32* __restrict__ offs,
                             u32* __restrict__ cursor, u32* __restrict__ total, int N) {
    __shared__ u32 wt[4];
    __shared__ u32 bbase;
    int tid = threadIdx.x, lane = tid & 63, wv = tid >> 6;
    int i = blockIdx.x * 256 + tid;
    u32 d = (i < N) ? deg[i] : 0u;
    u32 sc = d;
#pragma unroll
    for (int s = 1; s < 64; s <<= 1) { u32 o = __shfl_up(sc, s); if (lane >= s) sc += o; }
    if (lane == 63) wt[wv] = sc;
    __syncthreads();
    if (tid == 0) bbase = atomicAdd(total, wt[0] + wt[1] + wt[2] + wt[3]);
    __syncthreads();
    u32 wpre = 0;
    for (int w = 0; w < wv; ++w) wpre += wt[w];
    u32 off = bbase + wpre + sc - d;
    if (i < N) { offs[i] = off; cursor[i] = off; }
}

// Bucket-fill, packed metadata: edata[pos] = {src, rel, w_bits, 0}.
__global__ void fill_kernel(const int* __restrict__ ei, const int* __restrict__ et,
                            const u32* __restrict__ deg_src,
                            const u32* __restrict__ deg_dst,
                            const float* __restrict__ gate,
                            u32* __restrict__ cursor, uint4* __restrict__ edata, int E) {
    int e = blockIdx.x * 256 + threadIdx.x;
    if (e >= E) return;
    int src = ei[e];
    int dst = ei[E + e];
    int rel = et[e];
    float w = gate[rel] * rsqrtf(fmaxf((float)deg_src[src] * (float)deg_dst[dst], 1.0f));
    u32 pos = atomicAdd(&cursor[dst], 1u);
    edata[pos] = make_uint4((u32)src, (u32)rel, __float_as_uint(w), 0u);
}

// fp32 -> bf16 bulk convert (8 elems/thread, grid-stride).
__global__ void tobf_kernel(const float* __restrict__ src, u16* __restrict__ dst, int n8) {
    for (int i = blockIdx.x * 256 + threadIdx.x; i < n8; i += gridDim.x * 256) {
        const float* p = src + (size_t)i * 8;
        float4 a = *(const float4*)(p);
        float4 b = *(const float4*)(p + 4);
        u16 tmp[8] = {f2bf(a.x), f2bf(a.y), f2bf(a.z), f2bf(a.w),
                      f2bf(b.x), f2bf(b.y), f2bf(b.z), f2bf(b.w)};
        *(uint4*)(dst + (size_t)i * 8) = *(const uint4*)tmp;
    }
}

// One wave per node: agg row (bf16) into first 512B of d_out's 1KB slot + wsum.
template <int BF>
__global__ __launch_bounds__(256) void agg_kernel(
    const float* __restrict__ h, const u16* __restrict__ h_bf,
    const float* __restrict__ rel_emb, const u16* __restrict__ rel_bf,
    const u32* __restrict__ offs, const u32* __restrict__ deg_dst,
    const uint4* __restrict__ edata,
    u16* __restrict__ agg_bf, float* __restrict__ wsum_arr, int N) {
    int wv = threadIdx.x >> 6, lane = threadIdx.x & 63;
    int n = blockIdx.x * 4 + wv;
    if (n >= N) return;
    u32 off = offs[n];
    u32 dd = deg_dst[n];
    float4 acc = make_float4(0.f, 0.f, 0.f, 0.f);
    float wsum = 0.f;
    u32 e = 0;
    for (; e + 2 <= dd; e += 2) {   // 2x unroll for memory-level parallelism
        uint4 d0 = edata[off + e], d1 = edata[off + e + 1];
        float w0 = __uint_as_float(d0.z), w1 = __uint_as_float(d1.z);
        float4 h0, r0, h1, r1;
        if (BF) {
            h0 = bf4_to_f4(*(const uint2*)(h_bf + (size_t)d0.x * 256 + lane * 4));
            r0 = bf4_to_f4(*(const uint2*)(rel_bf + (size_t)d0.y * 256 + lane * 4));
            h1 = bf4_to_f4(*(const uint2*)(h_bf + (size_t)d1.x * 256 + lane * 4));
            r1 = bf4_to_f4(*(const uint2*)(rel_bf + (size_t)d1.y * 256 + lane * 4));
        } else {
            h0 = *(const float4*)(h + (size_t)d0.x * 256 + lane * 4);
            r0 = *(const float4*)(rel_emb + (size_t)d0.y * 256 + lane * 4);
            h1 = *(const float4*)(h + (size_t)d1.x * 256 + lane * 4);
            r1 = *(const float4*)(rel_emb + (size_t)d1.y * 256 + lane * 4);
        }
        acc.x += w0 * h0.x * r0.x + w1 * h1.x * r1.x;
        acc.y += w0 * h0.y * r0.y + w1 * h1.y * r1.y;
        acc.z += w0 * h0.z * r0.z + w1 * h1.z * r1.z;
        acc.w += w0 * h0.w * r0.w + w1 * h1.w * r1.w;
        wsum += w0 + w1;
    }
    if (e < dd) {
        uint4 d0 = edata[off + e];
        float w0 = __uint_as_float(d0.z);
        float4 h0, r0;
        if (BF) {
            h0 = bf4_to_f4(*(const uint2*)(h_bf + (size_t)d0.x * 256 + lane * 4));
            r0 = bf4_to_f4(*(const uint2*)(rel_bf + (size_t)d0.y * 256 + lane * 4));
        } else {
            h0 = *(const float4*)(h + (size_t)d0.x * 256 + lane * 4);
            r0 = *(const float4*)(rel_emb + (size_t)d0.y * 256 + lane * 4);
        }
        acc.x += w0 * h0.x * r0.x;
        acc.y += w0 * h0.y * r0.y;
        acc.z += w0 * h0.z * r0.z;
        acc.w += w0 * h0.w * r0.w;
        wsum += w0;
    }
    u32 lo = (u32)f2bf(acc.x) | ((u32)f2bf(acc.y) << 16);
    u32 hi = (u32)f2bf(acc.z) | ((u32)f2bf(acc.w) << 16);
    *(uint2*)(agg_bf + (size_t)n * 512 + lane * 4) = make_uint2(lo, hi);
    if (lane == 0) wsum_arr[n] = wsum;
}

// Single K=512 MFMA GEMM per 32-row block: x = [agg_row | h_row] (bf16, swizzled
// LDS: m*512 + (k ^ ((m&7)<<3))).  out[row][p] = acc[p] + c0[p] + c1[p]*ws[row].
// Kcomb rows are output-permuted, so stores are coalesced 64B segments.
template <int BF>
__global__ __launch_bounds__(256) void mega_kernel(
    float* __restrict__ dio, const u16* __restrict__ agg_bf,
    const u16* __restrict__ Kcomb,
    const float* __restrict__ h, const u16* __restrict__ h_bf,
    const float* __restrict__ wsum_arr,
    const float* __restrict__ c0, const float* __restrict__ c1, int N) {
    __shared__ __align__(16) u16 xs[32 * 512];  // 32 KiB bf16 tile
    const int tid = threadIdx.x;
    const int lane = tid & 63;
    const int wv = tid >> 6;        // wave owns output cols [wv*64, wv*64+64)
    const int l15 = lane & 15;
    const int kg = lane >> 4;       // k-group 0..3
    const int m0 = blockIdx.x * 32;
    const int jbase = wv * 64;

    // ---- stage [agg | h] rows -> swizzled LDS (128B per thread) ----
    {
        int m = tid >> 3;                 // 0..31
        int cb = (tid & 7) * 64;          // col chunk base (u16 units)
        int n = m0 + m;
        bool ok = n < N;
        const u16* arow = agg_bf + (size_t)n * 512;
#pragma unroll
        for (int q = 0; q < 8; ++q) {
            int k = cb + q * 8;
            uint4 v = make_uint4(0u, 0u, 0u, 0u);
            if (ok) {
                if (k < 256) {
                    v = *(const uint4*)(arow + k);
                } else if (BF) {
                    v = *(const uint4*)(h_bf + (size_t)n * 256 + (k - 256));
                } else {
                    const float* hp = h + (size_t)n * 256 + (k - 256);
                    float4 f0 = *(const float4*)hp, f1 = *(const float4*)(hp + 4);
                    u16 tmp[8] = {f2bf(f0.x), f2bf(f0.y), f2bf(f0.z), f2bf(f0.w),
                                  f2bf(f1.x), f2bf(f1.y), f2bf(f1.z), f2bf(f1.w)};
                    v = *(const uint4*)tmp;
                }
            }
            *(uint4*)&xs[m * 512 + (k ^ ((m & 7) << 3))] = v;
        }
    }
    __syncthreads();

    f32x4 acc[2][4];
#pragma unroll
    for (int mf = 0; mf < 2; ++mf)
#pragma unroll
        for (int nf = 0; nf < 4; ++nf) acc[mf][nf] = (f32x4)(0.f);

#pragma unroll
    for (int k0 = 0; k0 < 512; k0 += 32) {
        int kk = k0 + kg * 8;
        int ma = l15, mb = 16 + l15;
        bf16x8 a0 = *(const bf16x8*)&xs[ma * 512 + (kk ^ ((ma & 7) << 3))];
        bf16x8 a1 = *(const bf16x8*)&xs[mb * 512 + (kk ^ ((mb & 7) << 3))];
#pragma unroll
        for (int nf = 0; nf < 4; ++nf) {
            int p = jbase + nf * 16 + l15;
            bf16x8 b = *(const bf16x8*)(Kcomb + (size_t)p * 512 + kk);
            acc[0][nf] = __builtin_amdgcn_mfma_f32_16x16x32_bf16(a0, b, acc[0][nf], 0, 0, 0);
            acc[1][nf] = __builtin_amdgcn_mfma_f32_16x16x32_bf16(a1, b, acc[1][nf], 0, 0, 0);
        }
    }

    // ---- epilogue: y = acc + c0[p] + c1[p]*wsum[row]; coalesced store ----
#pragma unroll
    for (int nf = 0; nf < 4; ++nf) {
        int p = jbase + nf * 16 + l15;
        float b0 = c0[p];
        float b1 = c1[p];
#pragma unroll
        for (int mf = 0; mf < 2; ++mf) {
#pragma unroll
            for (int r = 0; r < 4; ++r) {
                int row = m0 + mf * 16 + kg * 4 + r;
                if (row < N)
                    dio[(size_t)row * 256 + p] = acc[mf][nf][r] + b0 + b1 * wsum_arr[row];
            }
        }
    }
}

static inline size_t align4(size_t x) { return (x + 3) & ~(size_t)3; }

extern "C" void kernel_launch(void* const* d_in, const int* in_sizes, int n_in,
                              void* d_out, int out_size, void* d_ws, size_t ws_size,
                              hipStream_t stream) {
    const float* h       = (const float*)d_in[0];
    const int*   ei      = (const int*)d_in[1];   // (2,E) row-major
    const int*   et      = (const int*)d_in[2];
    const float* rel_emb = (const float*)d_in[3];
    const float* msg_w   = (const float*)d_in[4];
    const float* msg_b   = (const float*)d_in[5];
    const float* upd_w   = (const float*)d_in[6];
    const float* upd_b   = (const float*)d_in[7];
    const float* gate_w  = (const float*)d_in[8];
    const float* gate_b  = (const float*)d_in[9];

    const int N = in_sizes[0] / 256;
    const int E = in_sizes[2];
    const int R = in_sizes[3] / 256;

    // workspace layout (u32 units); total+deg_src+deg_dst contiguous for memset
    u32* ws = (u32*)d_ws;
    size_t o = 0;
    u32* total    = ws + o; o += 4;
    u32* deg_src  = ws + o; o += align4((size_t)N);
    u32* deg_dst  = ws + o; o += align4((size_t)N);
    u32* offs     = ws + o; o += align4((size_t)N);
    u32* cursor   = ws + o; o += align4((size_t)N);
    float* wsum   = (float*)(ws + o); o += align4((size_t)N);
    float* gate   = (float*)(ws + o); o += align4((size_t)R);
    uint4* edata  = (uint4*)(ws + o); o += (size_t)4 * E;
    float* Mf     = (float*)(ws + o); o += 65536;   // 256x256 fp32
    u16* Kcomb    = (u16*)(ws + o); o += 65536;     // 256x512 bf16
    float* c0     = (float*)(ws + o); o += 256;
    float* c1     = (float*)(ws + o); o += 256;
    size_t need_base = o;
    u16* h_bf     = (u16*)(ws + o); o += (size_t)N * 128;
    u16* rel_bf   = (u16*)(ws + o); o += (size_t)R * 128;
    size_t need_bf = o;

    if (ws_size < need_base * 4) return;  // insufficient scratch -> fail loudly
    const bool use_bf = (ws_size >= need_bf * 4);

    float* out = (float*)d_out;
    u16* agg_bf = (u16*)d_out;   // bf16 rows at u16 stride 512 (half of each slot)

    // zero total + degree counters (contiguous)
    hipMemsetAsync(total, 0, (4 + 2 * align4((size_t)N)) * 4, stream);

    build_m_kernel<<<256, 256, 0, stream>>>(msg_w, Mf);
    build_comb_kernel<<<256, 256, 0, stream>>>(upd_w, upd_b, msg_b, Mf, Kcomb, c0, c1);
    gate_kernel<<<(R + 3) / 4, 256, 0, stream>>>(rel_emb, gate_w, gate_b, gate, R);
    degree_kernel<<<(E + 255) / 256, 256, 0, stream>>>(ei, E, deg_src, deg_dst);
    alloc_kernel<<<(N + 255) / 256, 256, 0, stream>>>(deg_dst, offs, cursor, total, N);
    if (use_bf) {
        tobf_kernel<<<1024, 256, 0, stream>>>(h, h_bf, N * 32);       // N*256/8
        tobf_kernel<<<64, 256, 0, stream>>>(rel_emb, rel_bf, R * 32); // R*256/8
    }
    fill_kernel<<<(E + 255) / 256, 256, 0, stream>>>(ei, et, deg_src, deg_dst, gate,
                                                     cursor, edata, E);
    const int nblk = (N + 31) / 32;
    if (use_bf) {
        agg_kernel<1><<<(N + 3) / 4, 256, 0, stream>>>(h, h_bf, rel_emb, rel_bf, offs,
                                                       deg_dst, edata, agg_bf, wsum, N);
        mega_kernel<1><<<nblk, 256, 0, stream>>>(out, agg_bf, Kcomb, h, h_bf,
                                                 wsum, c0, c1, N);
    } else {
        agg_kernel<0><<<(N + 3) / 4, 256, 0, stream>>>(h, h_bf, rel_emb, rel_bf, offs,
                                                       deg_dst, edata, agg_bf, wsum, N);
        mega_kernel<0><<<nblk, 256, 0, stream>>>(out, agg_bf, Kcomb, h, h_bf,
                                                 wsum, c0, c1, N);
    }
}

// Round 6
// 328.659 us; speedup vs baseline: 1.0952x; 1.0952x over previous
//
#include <hip/hip_runtime.h>
#include <math.h>

typedef unsigned int u32;
typedef unsigned short u16;
typedef __attribute__((ext_vector_type(8))) short bf16x8;   // 8 bf16 in 4 VGPRs
typedef __attribute__((ext_vector_type(4))) float f32x4;

__device__ inline u16 f2bf(float x) {  // round-to-nearest-even
    union { float f; u32 u; } v; v.f = x;
    u32 r = v.u + 0x7FFFu + ((v.u >> 16) & 1u);
    return (u16)(r >> 16);
}
__device__ inline float4 bf4_to_f4(uint2 p) {
    float4 r;
    r.x = __uint_as_float(p.x << 16);
    r.y = __uint_as_float(p.x & 0xffff0000u);
    r.z = __uint_as_float(p.y << 16);
    r.w = __uint_as_float(p.y & 0xffff0000u);
    return r;
}

// ---------------------------------------------------------------------------
// Clifford GNN message passing, fully linearized:
//   agg[n] = sum_e w_e*(h[src] .* r[rel]),  w_e = gate(rel)*norm(e)
//   out    = (Ku.Km).agg + Ku.h + ws*(Ku.msg_b) + upd_b
// One K=512 register-blocked MFMA GEMM on [agg_row | h_row], Kcomb=[Ku.Km|Ku]
// rows pre-permuted to make the output store channel-major-coalesced.
// GEMM uses NO LDS/barriers (round-5 post-mortem: LDS staging was pure
// latency overhead; the A tile is read once per wave anyway).
// ---------------------------------------------------------------------------

// Mf[k*256+i] = M[k][i] fp32 (message Clifford matrix, row k = output idx)
__global__ void build_m_kernel(const float* __restrict__ msg_w, float* __restrict__ Mf) {
    const int   s_tab[16] = {0,1,2,3, 1,0,3,2, 2,3,0,1, 3,2,1,0};
    const float g_tab[16] = {1.f,1.f,1.f,-1.f, 1.f,1.f,-1.f,1.f,
                             1.f,1.f,1.f,-1.f, 1.f,1.f,1.f,1.f};
    int idx = blockIdx.x * 256 + threadIdx.x;   // idx = k*256 + i
    int k = idx >> 8, i = idx & 255;
    int ob = k >> 6, oc = k & 63, ib = i >> 6, ic = i & 63;
    int t = ob * 4 + ib;
    Mf[idx] = g_tab[t] * msg_w[s_tab[t] * 4096 + oc * 64 + ic];
}

// Block p builds output-permuted row p of Kcomb (512 wide bf16) + c0[p], c1[p].
// j = (p&3)*64 + (p>>2);  Kcomb[p][0:256] = (U.M)[j][:], Kcomb[p][256:512]=U[j][:]
__global__ __launch_bounds__(256) void build_comb_kernel(
    const float* __restrict__ upd_w, const float* __restrict__ upd_b,
    const float* __restrict__ msg_b, const float* __restrict__ Mf,
    u16* __restrict__ Kcomb, float* __restrict__ c0, float* __restrict__ c1) {
    const int   s_tab[16] = {0,1,2,3, 1,0,3,2, 2,3,0,1, 3,2,1,0};
    const float g_tab[16] = {1.f,1.f,1.f,-1.f, 1.f,1.f,-1.f,1.f,
                             1.f,1.f,1.f,-1.f, 1.f,1.f,1.f,1.f};
    __shared__ float U_s[256];
    __shared__ float wred[4];
    int p = blockIdx.x;
    int j = (p & 3) * 64 + (p >> 2);
    int tid = threadIdx.x;
    {
        int ob = j >> 6, oc = j & 63, ib = tid >> 6, ic = tid & 63;
        int t = ob * 4 + ib;
        U_s[tid] = g_tab[t] * upd_w[s_tab[t] * 4096 + oc * 64 + ic];
    }
    __syncthreads();
    float acc = 0.f;
#pragma unroll 8
    for (int k = 0; k < 256; ++k) acc += U_s[k] * Mf[k * 256 + tid];
    Kcomb[(size_t)p * 512 + tid] = f2bf(acc);
    Kcomb[(size_t)p * 512 + 256 + tid] = f2bf(U_s[tid]);
    float part = U_s[tid] * msg_b[tid];
    int lane = tid & 63, wv = tid >> 6;
#pragma unroll
    for (int d = 32; d > 0; d >>= 1) part += __shfl_down(part, d);
    if (lane == 0) wred[wv] = part;
    __syncthreads();
    if (tid == 0) { c1[p] = wred[0] + wred[1] + wred[2] + wred[3]; c0[p] = upd_b[j]; }
}

// gate[r] = sigmoid( sum_j rel_emb[r, j] * gate_w[(j&63)*4 + (j>>6)] + gate_b )
__global__ void gate_kernel(const float* __restrict__ rel_emb,
                            const float* __restrict__ gate_w,
                            const float* __restrict__ gate_b,
                            float* __restrict__ gate, int R) {
    int wv = threadIdx.x >> 6, lane = threadIdx.x & 63;
    int r = blockIdx.x * 4 + wv;
    if (r >= R) return;
    float4 rv = *(const float4*)(rel_emb + (size_t)r * 256 + lane * 4);
    float s = 0.f;
    float rvv[4] = {rv.x, rv.y, rv.z, rv.w};
#pragma unroll
    for (int c = 0; c < 4; ++c) {
        int j = lane * 4 + c;
        s += rvv[c] * gate_w[(j & 63) * 4 + (j >> 6)];
    }
#pragma unroll
    for (int d = 32; d > 0; d >>= 1) s += __shfl_down(s, d);
    if (lane == 0) gate[r] = 1.0f / (1.0f + expf(-(s + gate_b[0])));
}

__global__ void degree_kernel(const int* __restrict__ ei, int E,
                              u32* __restrict__ deg_src, u32* __restrict__ deg_dst) {
    int e = blockIdx.x * 256 + threadIdx.x;
    if (e >= E) return;
    atomicAdd(&deg_src[ei[e]], 1u);
    atomicAdd(&deg_dst[ei[E + e]], 1u);
}

// Parallel bucket allocator (order irrelevant, only disjointness matters).
__global__ void alloc_kernel(const u32* __restrict__ deg, u32* __restrict__ offs,
                             u32* __restrict__ cursor, u32* __restrict__ total, int N) {
    __shared__ u32 wt[4];
    __shared__ u32 bbase;
    int tid = threadIdx.x, lane = tid & 63, wv = tid >> 6;
    int i = blockIdx.x * 256 + tid;
    u32 d = (i < N) ? deg[i] : 0u;
    u32 sc = d;
#pragma unroll
    for (int s = 1; s < 64; s <<= 1) { u32 o = __shfl_up(sc, s); if (lane >= s) sc += o; }
    if (lane == 63) wt[wv] = sc;
    __syncthreads();
    if (tid == 0) bbase = atomicAdd(total, wt[0] + wt[1] + wt[2] + wt[3]);
    __syncthreads();
    u32 wpre = 0;
    for (int w = 0; w < wv; ++w) wpre += wt[w];
    u32 off = bbase + wpre + sc - d;
    if (i < N) { offs[i] = off; cursor[i] = off; }
}

// Bucket-fill, packed metadata: edata[pos] = {src, rel, w_bits, 0}.
__global__ void fill_kernel(const int* __restrict__ ei, const int* __restrict__ et,
                            const u32* __restrict__ deg_src,
                            const u32* __restrict__ deg_dst,
                            const float* __restrict__ gate,
                            u32* __restrict__ cursor, uint4* __restrict__ edata, int E) {
    int e = blockIdx.x * 256 + threadIdx.x;
    if (e >= E) return;
    int src = ei[e];
    int dst = ei[E + e];
    int rel = et[e];
    float w = gate[rel] * rsqrtf(fmaxf((float)deg_src[src] * (float)deg_dst[dst], 1.0f));
    u32 pos = atomicAdd(&cursor[dst], 1u);
    edata[pos] = make_uint4((u32)src, (u32)rel, __float_as_uint(w), 0u);
}

// fp32 -> bf16 bulk convert (8 elems/thread, grid-stride).
__global__ void tobf_kernel(const float* __restrict__ src, u16* __restrict__ dst, int n8) {
    for (int i = blockIdx.x * 256 + threadIdx.x; i < n8; i += gridDim.x * 256) {
        const float* p = src + (size_t)i * 8;
        float4 a = *(const float4*)(p);
        float4 b = *(const float4*)(p + 4);
        u16 tmp[8] = {f2bf(a.x), f2bf(a.y), f2bf(a.z), f2bf(a.w),
                      f2bf(b.x), f2bf(b.y), f2bf(b.z), f2bf(b.w)};
        *(uint4*)(dst + (size_t)i * 8) = *(const uint4*)tmp;
    }
}

// One wave per node: agg row (bf16) into first 512B of d_out's 1KB slot + wsum.
template <int BF>
__global__ __launch_bounds__(256) void agg_kernel(
    const float* __restrict__ h, const u16* __restrict__ h_bf,
    const float* __restrict__ rel_emb, const u16* __restrict__ rel_bf,
    const u32* __restrict__ offs, const u32* __restrict__ deg_dst,
    const uint4* __restrict__ edata,
    u16* __restrict__ agg_bf, float* __restrict__ wsum_arr, int N) {
    int wv = threadIdx.x >> 6, lane = threadIdx.x & 63;
    int n = blockIdx.x * 4 + wv;
    if (n >= N) return;
    u32 off = offs[n];
    u32 dd = deg_dst[n];
    float4 acc = make_float4(0.f, 0.f, 0.f, 0.f);
    float wsum = 0.f;
    u32 e = 0;
    for (; e + 2 <= dd; e += 2) {   // 2x unroll for memory-level parallelism
        uint4 d0 = edata[off + e], d1 = edata[off + e + 1];
        float w0 = __uint_as_float(d0.z), w1 = __uint_as_float(d1.z);
        float4 h0, r0, h1, r1;
        if (BF) {
            h0 = bf4_to_f4(*(const uint2*)(h_bf + (size_t)d0.x * 256 + lane * 4));
            r0 = bf4_to_f4(*(const uint2*)(rel_bf + (size_t)d0.y * 256 + lane * 4));
            h1 = bf4_to_f4(*(const uint2*)(h_bf + (size_t)d1.x * 256 + lane * 4));
            r1 = bf4_to_f4(*(const uint2*)(rel_bf + (size_t)d1.y * 256 + lane * 4));
        } else {
            h0 = *(const float4*)(h + (size_t)d0.x * 256 + lane * 4);
            r0 = *(const float4*)(rel_emb + (size_t)d0.y * 256 + lane * 4);
            h1 = *(const float4*)(h + (size_t)d1.x * 256 + lane * 4);
            r1 = *(const float4*)(rel_emb + (size_t)d1.y * 256 + lane * 4);
        }
        acc.x += w0 * h0.x * r0.x + w1 * h1.x * r1.x;
        acc.y += w0 * h0.y * r0.y + w1 * h1.y * r1.y;
        acc.z += w0 * h0.z * r0.z + w1 * h1.z * r1.z;
        acc.w += w0 * h0.w * r0.w + w1 * h1.w * r1.w;
        wsum += w0 + w1;
    }
    if (e < dd) {
        uint4 d0 = edata[off + e];
        float w0 = __uint_as_float(d0.z);
        float4 h0, r0;
        if (BF) {
            h0 = bf4_to_f4(*(const uint2*)(h_bf + (size_t)d0.x * 256 + lane * 4));
            r0 = bf4_to_f4(*(const uint2*)(rel_bf + (size_t)d0.y * 256 + lane * 4));
        } else {
            h0 = *(const float4*)(h + (size_t)d0.x * 256 + lane * 4);
            r0 = *(const float4*)(rel_emb + (size_t)d0.y * 256 + lane * 4);
        }
        acc.x += w0 * h0.x * r0.x;
        acc.y += w0 * h0.y * r0.y;
        acc.z += w0 * h0.z * r0.z;
        acc.w += w0 * h0.w * r0.w;
        wsum += w0;
    }
    u32 lo = (u32)f2bf(acc.x) | ((u32)f2bf(acc.y) << 16);
    u32 hi = (u32)f2bf(acc.z) | ((u32)f2bf(acc.w) << 16);
    *(uint2*)(agg_bf + (size_t)n * 512 + lane * 4) = make_uint2(lo, hi);
    if (lane == 0) wsum_arr[n] = wsum;
}

// Register-blocked K=512 GEMM, NO LDS, NO barriers. Block = 64 rows, 4 waves;
// wave = 64 rows x 64 cols (acc 4x4 frags = 64 AGPR). A-frags direct from
// global (agg slots in d_out at 1KB stride, then h_bf at 512B stride); each
// A-load instruction = 16 rows x 64B contiguous lines. Latency hidden by
// occupancy (no VGPR-heavy staging, no convoys).
// out[row][p] = acc + c0[p] + c1[p]*wsum[row]  (Kcomb rows output-permuted).
template <int BF>
__global__ __launch_bounds__(256) void gemm_reg_kernel(
    float* __restrict__ dio, const u16* __restrict__ agg_bf,
    const u16* __restrict__ Kcomb,
    const float* __restrict__ h, const u16* __restrict__ h_bf,
    const float* __restrict__ wsum_arr,
    const float* __restrict__ c0, const float* __restrict__ c1, int N) {
    const int lane = threadIdx.x & 63;
    const int wv = threadIdx.x >> 6;      // wave owns output cols [wv*64, +64)
    const int l15 = lane & 15;
    const int kg = lane >> 4;             // k-group 0..3
    const int m0 = blockIdx.x * 64;
    const int pbase = wv * 64;

    f32x4 acc[4][4];
#pragma unroll
    for (int f = 0; f < 4; ++f)
#pragma unroll
        for (int nf = 0; nf < 4; ++nf) acc[f][nf] = (f32x4)(0.f);

    int rowA[4];
#pragma unroll
    for (int f = 0; f < 4; ++f) {
        int r = m0 + f * 16 + l15;
        rowA[f] = (r < N) ? r : (N - 1);   // clamp: avoids OOB, result masked at store
    }
    const u16* bbase_p = Kcomb + (size_t)pbase * 512 + (size_t)l15 * 512 + kg * 8;

    // ---- first half: A = agg rows (d_out slots, u16 stride 512) ----
#pragma unroll 2
    for (int k0 = 0; k0 < 256; k0 += 32) {
        int kk = k0 + kg * 8;
        bf16x8 a[4], b[4];
#pragma unroll
        for (int f = 0; f < 4; ++f)
            a[f] = *(const bf16x8*)(agg_bf + (size_t)rowA[f] * 512 + kk);
#pragma unroll
        for (int nf = 0; nf < 4; ++nf)
            b[nf] = *(const bf16x8*)(bbase_p + (size_t)nf * 16 * 512 + k0);
#pragma unroll
        for (int f = 0; f < 4; ++f)
#pragma unroll
            for (int nf = 0; nf < 4; ++nf)
                acc[f][nf] = __builtin_amdgcn_mfma_f32_16x16x32_bf16(a[f], b[nf], acc[f][nf], 0, 0, 0);
    }
    // ---- second half: A = h rows ----
#pragma unroll 2
    for (int k0 = 256; k0 < 512; k0 += 32) {
        int kh = (k0 - 256) + kg * 8;
        bf16x8 a[4], b[4];
        if (BF) {
#pragma unroll
            for (int f = 0; f < 4; ++f)
                a[f] = *(const bf16x8*)(h_bf + (size_t)rowA[f] * 256 + kh);
        } else {
#pragma unroll
            for (int f = 0; f < 4; ++f) {
                const float* hp = h + (size_t)rowA[f] * 256 + kh;
                float4 f0 = *(const float4*)hp, f1 = *(const float4*)(hp + 4);
                u16 tmp[8] = {f2bf(f0.x), f2bf(f0.y), f2bf(f0.z), f2bf(f0.w),
                              f2bf(f1.x), f2bf(f1.y), f2bf(f1.z), f2bf(f1.w)};
                a[f] = *(const bf16x8*)tmp;
            }
        }
#pragma unroll
        for (int nf = 0; nf < 4; ++nf)
            b[nf] = *(const bf16x8*)(bbase_p + (size_t)nf * 16 * 512 + k0);
#pragma unroll
        for (int f = 0; f < 4; ++f)
#pragma unroll
            for (int nf = 0; nf < 4; ++nf)
                acc[f][nf] = __builtin_amdgcn_mfma_f32_16x16x32_bf16(a[f], b[nf], acc[f][nf], 0, 0, 0);
    }

    // ---- epilogue: y = acc + c0[p] + c1[p]*wsum[row]; coalesced-ish store ----
    float b0[4], b1[4];
#pragma unroll
    for (int nf = 0; nf < 4; ++nf) {
        int p = pbase + nf * 16 + l15;
        b0[nf] = c0[p];
        b1[nf] = c1[p];
    }
#pragma unroll
    for (int f = 0; f < 4; ++f) {
#pragma unroll
        for (int r = 0; r < 4; ++r) {
            int row = m0 + f * 16 + kg * 4 + r;
            if (row >= N) continue;
            float wsv = wsum_arr[row];
#pragma unroll
            for (int nf = 0; nf < 4; ++nf) {
                int p = pbase + nf * 16 + l15;
                dio[(size_t)row * 256 + p] = acc[f][nf][r] + b0[nf] + b1[nf] * wsv;
            }
        }
    }
}

static inline size_t align4(size_t x) { return (x + 3) & ~(size_t)3; }

extern "C" void kernel_launch(void* const* d_in, const int* in_sizes, int n_in,
                              void* d_out, int out_size, void* d_ws, size_t ws_size,
                              hipStream_t stream) {
    const float* h       = (const float*)d_in[0];
    const int*   ei      = (const int*)d_in[1];   // (2,E) row-major
    const int*   et      = (const int*)d_in[2];
    const float* rel_emb = (const float*)d_in[3];
    const float* msg_w   = (const float*)d_in[4];
    const float* msg_b   = (const float*)d_in[5];
    const float* upd_w   = (const float*)d_in[6];
    const float* upd_b   = (const float*)d_in[7];
    const float* gate_w  = (const float*)d_in[8];
    const float* gate_b  = (const float*)d_in[9];

    const int N = in_sizes[0] / 256;
    const int E = in_sizes[2];
    const int R = in_sizes[3] / 256;

    // workspace layout (u32 units); total+deg_src+deg_dst contiguous for memset
    u32* ws = (u32*)d_ws;
    size_t o = 0;
    u32* total    = ws + o; o += 4;
    u32* deg_src  = ws + o; o += align4((size_t)N);
    u32* deg_dst  = ws + o; o += align4((size_t)N);
    u32* offs     = ws + o; o += align4((size_t)N);
    u32* cursor   = ws + o; o += align4((size_t)N);
    float* wsum   = (float*)(ws + o); o += align4((size_t)N);
    float* gate   = (float*)(ws + o); o += align4((size_t)R);
    uint4* edata  = (uint4*)(ws + o); o += (size_t)4 * E;
    float* Mf     = (float*)(ws + o); o += 65536;   // 256x256 fp32
    u16* Kcomb    = (u16*)(ws + o); o += 65536;     // 256x512 bf16
    float* c0     = (float*)(ws + o); o += 256;
    float* c1     = (float*)(ws + o); o += 256;
    size_t need_base = o;
    u16* h_bf     = (u16*)(ws + o); o += (size_t)N * 128;
    u16* rel_bf   = (u16*)(ws + o); o += (size_t)R * 128;
    size_t need_bf = o;

    if (ws_size < need_base * 4) return;  // insufficient scratch -> fail loudly
    const bool use_bf = (ws_size >= need_bf * 4);

    float* out = (float*)d_out;
    u16* agg_bf = (u16*)d_out;   // bf16 rows at u16 stride 512 (half of each slot)

    // zero total + degree counters (contiguous)
    hipMemsetAsync(total, 0, (4 + 2 * align4((size_t)N)) * 4, stream);

    build_m_kernel<<<256, 256, 0, stream>>>(msg_w, Mf);
    build_comb_kernel<<<256, 256, 0, stream>>>(upd_w, upd_b, msg_b, Mf, Kcomb, c0, c1);
    gate_kernel<<<(R + 3) / 4, 256, 0, stream>>>(rel_emb, gate_w, gate_b, gate, R);
    degree_kernel<<<(E + 255) / 256, 256, 0, stream>>>(ei, E, deg_src, deg_dst);
    alloc_kernel<<<(N + 255) / 256, 256, 0, stream>>>(deg_dst, offs, cursor, total, N);
    if (use_bf) {
        tobf_kernel<<<1024, 256, 0, stream>>>(h, h_bf, N * 32);       // N*256/8
        tobf_kernel<<<64, 256, 0, stream>>>(rel_emb, rel_bf, R * 32); // R*256/8
    }
    fill_kernel<<<(E + 255) / 256, 256, 0, stream>>>(ei, et, deg_src, deg_dst, gate,
                                                     cursor, edata, E);
    const int nblk = (N + 63) / 64;
    if (use_bf) {
        agg_kernel<1><<<(N + 3) / 4, 256, 0, stream>>>(h, h_bf, rel_emb, rel_bf, offs,
                                                       deg_dst, edata, agg_bf, wsum, N);
        gemm_reg_kernel<1><<<nblk, 256, 0, stream>>>(out, agg_bf, Kcomb, h, h_bf,
                                                     wsum, c0, c1, N);
    } else {
        agg_kernel<0><<<(N + 3) / 4, 256, 0, stream>>>(h, h_bf, rel_emb, rel_bf, offs,
                                                       deg_dst, edata, agg_bf, wsum, N);
        gemm_reg_kernel<0><<<nblk, 256, 0, stream>>>(out, agg_bf, Kcomb, h, h_bf,
                                                     wsum, c0, c1, N);
    }
}